// Round 1
// baseline (32865.421 us; speedup 1.0000x reference)
//
#include <hip/hip_runtime.h>

#define D_IN   1024
#define D_H    512
#define M_BANK 100
#define BATCH  128
#define NCOL   1224   // 100 (read logits) + 100 (write logits) + 512 (c) + 512 (pre_h)
#define NPAD   1280
#define KTOT   1536
#define KSPLIT 4
#define KCHUNK 384    // 1536/4

// ---------------------------------------------------------------------------
// K1: z_p[kp] = xh @ W_big[kchunk]   (fp32 tiled GEMM, split-K)
//   columns: [0,100)   -> xh @ W_rp        (read logits, bias added in K2)
//            [100,200) -> xh @ W_wp        (write logits)
//            [200,712) -> xh @ W_c         (content pre-act)
//            [712,1224)-> x@Wxh + h@Whh    (pre_h)
//   xh[b,k] = k<1024 ? frames[b,t,k] : h_t[b,k-1024]  (h_t read from out[b,t-1,:])
// grid (NPAD/64, BATCH/32, KSPLIT), block 128, 4x4 register tile
// ---------------------------------------------------------------------------
__global__ void k_gemm1(const float* __restrict__ frames,
                        const float* __restrict__ W_c,
                        const float* __restrict__ W_rp,
                        const float* __restrict__ W_wp,
                        const float* __restrict__ Wxh,
                        const float* __restrict__ Whh,
                        const float* __restrict__ out,  // h_t source (t-1 row)
                        float* __restrict__ zp,
                        int t, int T, int TF) {
  __shared__ float As[32][33];   // +1 pad: A reads are row-indexed at fixed k
  __shared__ float Bs[32][64];
  const int jt  = blockIdx.x;        // 0..19
  const int mt  = blockIdx.y;        // 0..3
  const int kp  = blockIdx.z;        // 0..3
  const int tid = threadIdx.x;
  const int tx  = tid & 15;          // col group (4 cols)
  const int ty  = tid >> 4;          // row group (4 rows), 0..7
  const int j0  = jt * 64;
  const int m0  = mt * 32;

  float acc[4][4] = {};

  for (int kt = 0; kt < KCHUNK; kt += 32) {
    const int k0 = kp * KCHUNK + kt;
    // ---- stage A tile: 32 rows x 32 k
    {
      const int kg = (tid & 7) * 4;
      const int r0 = tid >> 3;       // 0..15
      #pragma unroll
      for (int rr = r0; rr < 32; rr += 16) {
        const int row = m0 + rr;
        const int k   = k0 + kg;
        float4 v;
        if (k < D_IN) {
          v = *reinterpret_cast<const float4*>(&frames[((size_t)row * TF + t) * D_IN + k]);
        } else if (t == 0) {
          v = make_float4(0.f, 0.f, 0.f, 0.f);
        } else {
          v = *reinterpret_cast<const float4*>(&out[((size_t)row * T + (t - 1)) * D_H + (k - D_IN)]);
        }
        As[rr][kg + 0] = v.x; As[rr][kg + 1] = v.y;
        As[rr][kg + 2] = v.z; As[rr][kg + 3] = v.w;
      }
    }
    // ---- stage B tile: 32 k x 64 j  (composite weight mapping)
    {
      const int jg = (tid & 15) * 4;
      const int r0 = tid >> 4;       // 0..7
      #pragma unroll
      for (int rr = r0; rr < 32; rr += 8) {
        const int k = k0 + rr;
        const int j = j0 + jg;
        float4 v;
        if (j < 100) {
          v = *reinterpret_cast<const float4*>(&W_rp[(size_t)k * M_BANK + j]);
        } else if (j < 200) {
          v = *reinterpret_cast<const float4*>(&W_wp[(size_t)k * M_BANK + (j - 100)]);
        } else if (j < 712) {
          v = *reinterpret_cast<const float4*>(&W_c[(size_t)k * D_H + (j - 200)]);
        } else if (j < NCOL) {
          const int jj = j - 712;
          if (k < D_IN) v = *reinterpret_cast<const float4*>(&Wxh[(size_t)k * D_H + jj]);
          else          v = *reinterpret_cast<const float4*>(&Whh[(size_t)(k - D_IN) * D_H + jj]);
        } else {
          v = make_float4(0.f, 0.f, 0.f, 0.f);
        }
        *reinterpret_cast<float4*>(&Bs[rr][jg]) = v;
      }
    }
    __syncthreads();
    #pragma unroll 8
    for (int k = 0; k < 32; ++k) {
      const float4 b4 = *reinterpret_cast<const float4*>(&Bs[k][tx * 4]);
      #pragma unroll
      for (int i = 0; i < 4; ++i) {
        const float a = As[ty * 4 + i][k];
        acc[i][0] += a * b4.x; acc[i][1] += a * b4.y;
        acc[i][2] += a * b4.z; acc[i][3] += a * b4.w;
      }
    }
    __syncthreads();
  }
  // ---- store partial z
  #pragma unroll
  for (int i = 0; i < 4; ++i) {
    const int row = m0 + ty * 4 + i;
    float4 v = make_float4(acc[i][0], acc[i][1], acc[i][2], acc[i][3]);
    *reinterpret_cast<float4*>(&zp[(((size_t)kp * BATCH) + row) * NPAD + j0 + tx * 4]) = v;
  }
}

// ---------------------------------------------------------------------------
// K2: per-step epilogue, partitioned (batch-tile 8) x (h-slice 32).
//   softmax(read/write logits) -> ar, aw (per 32-lane group, redundant per slice)
//   c  = relu(zc + b_c)
//   cW = c @ Wrh[:, slice]
//   h' = relu(pre_h + bh + ar @ M2[:, slice])       (M2 = mem @ Wrh)
//   M2 = aw*cW + (1-aw)*M2                          (fused with the ar@M2 pass)
// grid (D_H/32, BATCH/8), block 256 (= 8 batch x 32 lanes)
// ---------------------------------------------------------------------------
__global__ void k_phase2(const float* __restrict__ zp,
                         const float* __restrict__ Wrh,
                         const float* __restrict__ b_rp,
                         const float* __restrict__ b_wp,
                         const float* __restrict__ b_c,
                         const float* __restrict__ bh,
                         float* __restrict__ M2,
                         float* __restrict__ out,
                         int t, int T) {
  __shared__ float ar_s[8][100];
  __shared__ float aw_s[8][100];
  __shared__ float c_s[8][512];
  const int tid  = threadIdx.x;
  const int lane = tid & 31;
  const int bl   = tid >> 5;               // 0..7
  const int b0   = blockIdx.y * 8;
  const int b_g  = b0 + bl;
  const int s_g  = blockIdx.x * 32 + lane;

  // ---- softmaxes (32 lanes cooperate per batch row; which=0 read, 1 write)
  #pragma unroll
  for (int which = 0; which < 2; ++which) {
    float lv[4];
    float mx = -1e30f;
    #pragma unroll
    for (int i = 0; i < 4; ++i) {
      const int m = lane + i * 32;
      float l = -1e30f;
      if (m < M_BANK) {
        l = which ? b_wp[m] : b_rp[m];
        const int col = which ? (100 + m) : m;
        #pragma unroll
        for (int p = 0; p < KSPLIT; ++p)
          l += zp[(((size_t)p * BATCH) + b_g) * NPAD + col];
      }
      lv[i] = l;
      mx = fmaxf(mx, l);
    }
    #pragma unroll
    for (int o = 16; o; o >>= 1) mx = fmaxf(mx, __shfl_xor(mx, o, 32));
    float sum = 0.f;
    #pragma unroll
    for (int i = 0; i < 4; ++i) {
      const float e = (lane + i * 32 < M_BANK) ? __expf(lv[i] - mx) : 0.f;
      lv[i] = e;
      sum += e;
    }
    #pragma unroll
    for (int o = 16; o; o >>= 1) sum += __shfl_xor(sum, o, 32);
    const float inv = 1.0f / sum;
    #pragma unroll
    for (int i = 0; i < 4; ++i) {
      const int m = lane + i * 32;
      if (m < M_BANK) {
        if (which) aw_s[bl][m] = lv[i] * inv;
        else       ar_s[bl][m] = lv[i] * inv;
      }
    }
  }
  // ---- stage c = relu(zc + b_c) for this block's 8 batches
  for (int idx = tid; idx < 8 * 512; idx += 256) {
    const int b = idx >> 9, k = idx & 511;
    float v = b_c[k];
    #pragma unroll
    for (int p = 0; p < KSPLIT; ++p)
      v += zp[(((size_t)p * BATCH) + (b0 + b)) * NPAD + 200 + k];
    c_s[b][k] = fmaxf(v, 0.f);
  }
  __syncthreads();

  // ---- cW[b, s_g] = c[b,:] @ Wrh[:, s_g]
  float cw = 0.f;
  #pragma unroll 4
  for (int k = 0; k < 512; ++k) cw += c_s[bl][k] * Wrh[(size_t)k * D_H + s_g];

  // ---- h' and fused M2 read-modify-write
  float hacc = bh[s_g];
  #pragma unroll
  for (int p = 0; p < KSPLIT; ++p)
    hacc += zp[(((size_t)p * BATCH) + b_g) * NPAD + 712 + s_g];
  float racc = 0.f;
  for (int m = 0; m < M_BANK; ++m) {
    const size_t idx = (((size_t)b_g * M_BANK) + m) * D_H + s_g;
    const float v = M2[idx];
    racc += ar_s[bl][m] * v;
    const float w = aw_s[bl][m];
    M2[idx] = w * cw + (1.0f - w) * v;
  }
  const float h = fmaxf(hacc + racc, 0.f);
  out[((size_t)b_g * T + t) * D_H + s_g] = h;
}

// ---------------------------------------------------------------------------
extern "C" void kernel_launch(void* const* d_in, const int* in_sizes, int n_in,
                              void* d_out, int out_size, void* d_ws, size_t ws_size,
                              hipStream_t stream) {
  const float* frames = (const float*)d_in[0];
  const float* W_c    = (const float*)d_in[1];
  const float* b_c    = (const float*)d_in[2];
  const float* W_rp   = (const float*)d_in[3];
  const float* b_rp   = (const float*)d_in[4];
  const float* W_wp   = (const float*)d_in[5];
  const float* b_wp   = (const float*)d_in[6];
  const float* Wxh    = (const float*)d_in[7];
  const float* Wrh    = (const float*)d_in[8];
  const float* Whh    = (const float*)d_in[9];
  const float* bh     = (const float*)d_in[10];
  float* out = (float*)d_out;

  const int TF = in_sizes[0] / (BATCH * D_IN);   // frames' T dim (256)
  const int T  = out_size / (BATCH * D_H);       // nImg steps

  const size_t M2_BYTES = (size_t)BATCH * M_BANK * D_H * sizeof(float);  // 26.2 MB
  float* M2 = (float*)d_ws;
  float* zp = (float*)((char*)d_ws + M2_BYTES);  // KSPLIT * BATCH * NPAD fp32 (2.6 MB)

  // mem0 = 0  =>  M2_0 = mem0 @ Wrh = 0  (must re-init every call: M2 is carried state)
  hipMemsetAsync(M2, 0, M2_BYTES, stream);

  for (int t = 0; t < T; ++t) {
    k_gemm1<<<dim3(NPAD / 64, BATCH / 32, KSPLIT), 128, 0, stream>>>(
        frames, W_c, W_rp, W_wp, Wxh, Whh, out, zp, t, T, TF);
    k_phase2<<<dim3(D_H / 32, BATCH / 8), 256, 0, stream>>>(
        zp, Wrh, b_rp, b_wp, b_c, bh, M2, out, t, T);
  }
}

// Round 3
// 11900.916 us; speedup vs baseline: 2.7616x; 2.7616x over previous
//
#include <hip/hip_runtime.h>

#define D_IN   1024
#define D_H    512
#define M_BANK 100
#define BATCH  128
#define NCOL   1224   // 100 rp | 100 wp | 512 c | 512 pre_h
#define NPAD   1280
#define KSH    4      // split-K for the per-step h-GEMM (K=512 -> 128 each)

// composite weight fetch: virtual big matrix W[1536][1280]
//   cols [0,100)=W_rp  [100,200)=W_wp  [200,712)=W_c  [712,1224)=Wxh/Whh  [1224,1280)=0
__device__ __forceinline__ float4 wload(const float* __restrict__ W_c,
                                        const float* __restrict__ W_rp,
                                        const float* __restrict__ W_wp,
                                        const float* __restrict__ Wxh,
                                        const float* __restrict__ Whh,
                                        int k, int j) {
  if (j < 100)  return *reinterpret_cast<const float4*>(&W_rp[k * M_BANK + j]);
  if (j < 200)  return *reinterpret_cast<const float4*>(&W_wp[k * M_BANK + (j - 100)]);
  if (j < 712)  return *reinterpret_cast<const float4*>(&W_c[k * D_H + (j - 200)]);
  if (j < NCOL) return (k < D_IN)
                    ? *reinterpret_cast<const float4*>(&Wxh[k * D_H + (j - 712)])
                    : *reinterpret_cast<const float4*>(&Whh[(k - D_IN) * D_H + (j - 712)]);
  return make_float4(0.f, 0.f, 0.f, 0.f);
}

// ---------------------------------------------------------------------------
// k_zx: hoisted x-GEMM for a chunk of CH steps.
//   zx[(b*CH+tc), j] = x[b, t0+tc, :] @ W[0:1024, j]
// grid (NPAD/64, BATCH*CH/64), block 128; 64x64 tile, 4 rows x 8 cols / thread
// ---------------------------------------------------------------------------
__global__ void k_zx(const float* __restrict__ frames,
                     const float* __restrict__ W_c,
                     const float* __restrict__ W_rp,
                     const float* __restrict__ W_wp,
                     const float* __restrict__ Wxh,
                     const float* __restrict__ Whh,
                     float* __restrict__ zx,
                     int t0, int CH, int lgCH, int TF) {
  __shared__ float Ast[32][68];   // transposed A tile [k][row]
  __shared__ float Bs[32][64];
  const int tid = threadIdx.x;
  const int j0 = blockIdx.x * 64;
  const int r0 = blockIdx.y * 64;
  const int tx = tid & 7;         // 8 cols
  const int ty = tid >> 3;        // 16 row-groups of 4

  float acc[4][8] = {};

  for (int k0 = 0; k0 < D_IN; k0 += 32) {
    #pragma unroll
    for (int l = 0; l < 4; ++l) {               // stage A (transpose into LDS)
      const int row = (tid >> 3) + l * 16;
      const int kg  = (tid & 7) * 4;
      const int r   = r0 + row;
      const int b   = r >> lgCH;
      const int tc  = r & (CH - 1);
      const float4 v = *reinterpret_cast<const float4*>(
          &frames[((size_t)(b * TF + t0 + tc)) * D_IN + k0 + kg]);
      Ast[kg + 0][row] = v.x; Ast[kg + 1][row] = v.y;
      Ast[kg + 2][row] = v.z; Ast[kg + 3][row] = v.w;
    }
    #pragma unroll
    for (int l = 0; l < 4; ++l) {               // stage B
      const int k  = (tid >> 4) + l * 8;
      const int jg = (tid & 15) * 4;
      const float4 v = wload(W_c, W_rp, W_wp, Wxh, Whh, k0 + k, j0 + jg);
      Bs[k][jg + 0] = v.x; Bs[k][jg + 1] = v.y;
      Bs[k][jg + 2] = v.z; Bs[k][jg + 3] = v.w;
    }
    __syncthreads();
    #pragma unroll 8
    for (int k = 0; k < 32; ++k) {
      const float4 bA = *reinterpret_cast<const float4*>(&Bs[k][tx * 8]);
      const float4 bB = *reinterpret_cast<const float4*>(&Bs[k][tx * 8 + 4]);
      #pragma unroll
      for (int i = 0; i < 4; ++i) {
        const float a = Ast[k][ty * 4 + i];
        acc[i][0] += a * bA.x; acc[i][1] += a * bA.y;
        acc[i][2] += a * bA.z; acc[i][3] += a * bA.w;
        acc[i][4] += a * bB.x; acc[i][5] += a * bB.y;
        acc[i][6] += a * bB.z; acc[i][7] += a * bB.w;
      }
    }
    __syncthreads();
  }
  #pragma unroll
  for (int i = 0; i < 4; ++i) {
    const size_t r = r0 + ty * 4 + i;
    float4 va = make_float4(acc[i][0], acc[i][1], acc[i][2], acc[i][3]);
    float4 vb = make_float4(acc[i][4], acc[i][5], acc[i][6], acc[i][7]);
    *reinterpret_cast<float4*>(&zx[r * NPAD + j0 + tx * 8]) = va;
    *reinterpret_cast<float4*>(&zx[r * NPAD + j0 + tx * 8 + 4]) = vb;
  }
}

// ---------------------------------------------------------------------------
// k_zh: per-step h-GEMM (split-K): zhp[kp][b, j] = h_{t-1}[b, kslice] @ W[1024+kslice, j]
// grid (NPAD/64, BATCH/64, KSH), block 128; same tile as k_zx
// ---------------------------------------------------------------------------
__global__ void k_zh(const float* __restrict__ hsrc,   // = out
                     const float* __restrict__ W_c,
                     const float* __restrict__ W_rp,
                     const float* __restrict__ W_wp,
                     const float* __restrict__ Wxh,
                     const float* __restrict__ Whh,
                     float* __restrict__ zhp,
                     int t, int T) {
  __shared__ float Ast[32][68];
  __shared__ float Bs[32][64];
  const int tid = threadIdx.x;
  const int j0 = blockIdx.x * 64;
  const int r0 = blockIdx.y * 64;
  const int kp = blockIdx.z;
  const int tx = tid & 7;
  const int ty = tid >> 3;

  float acc[4][8] = {};

  for (int kt = 0; kt < 128; kt += 32) {
    const int k0 = kp * 128 + kt;
    #pragma unroll
    for (int l = 0; l < 4; ++l) {
      const int row = (tid >> 3) + l * 16;
      const int kg  = (tid & 7) * 4;
      const float4 v = *reinterpret_cast<const float4*>(
          &hsrc[((size_t)(r0 + row) * T + (t - 1)) * D_H + k0 + kg]);
      Ast[kg + 0][row] = v.x; Ast[kg + 1][row] = v.y;
      Ast[kg + 2][row] = v.z; Ast[kg + 3][row] = v.w;
    }
    #pragma unroll
    for (int l = 0; l < 4; ++l) {
      const int k  = (tid >> 4) + l * 8;
      const int jg = (tid & 15) * 4;
      const float4 v = wload(W_c, W_rp, W_wp, Wxh, Whh, D_IN + k0 + k, j0 + jg);
      Bs[k][jg + 0] = v.x; Bs[k][jg + 1] = v.y;
      Bs[k][jg + 2] = v.z; Bs[k][jg + 3] = v.w;
    }
    __syncthreads();
    #pragma unroll 8
    for (int k = 0; k < 32; ++k) {
      const float4 bA = *reinterpret_cast<const float4*>(&Bs[k][tx * 8]);
      const float4 bB = *reinterpret_cast<const float4*>(&Bs[k][tx * 8 + 4]);
      #pragma unroll
      for (int i = 0; i < 4; ++i) {
        const float a = Ast[k][ty * 4 + i];
        acc[i][0] += a * bA.x; acc[i][1] += a * bA.y;
        acc[i][2] += a * bA.z; acc[i][3] += a * bA.w;
        acc[i][4] += a * bB.x; acc[i][5] += a * bB.y;
        acc[i][6] += a * bB.z; acc[i][7] += a * bB.w;
      }
    }
    __syncthreads();
  }
  #pragma unroll
  for (int i = 0; i < 4; ++i) {
    const size_t r = (size_t)kp * BATCH + r0 + ty * 4 + i;
    float4 va = make_float4(acc[i][0], acc[i][1], acc[i][2], acc[i][3]);
    float4 vb = make_float4(acc[i][4], acc[i][5], acc[i][6], acc[i][7]);
    *reinterpret_cast<float4*>(&zhp[r * NPAD + j0 + tx * 8]) = va;
    *reinterpret_cast<float4*>(&zhp[r * NPAD + j0 + tx * 8 + 4]) = vb;
  }
}

// ---------------------------------------------------------------------------
// k_phase2: softmaxes, c, cw = c@Wrh, h' = relu(pre_h + ar@M2), M2 blend.
// grid (D_H/128, BATCH/2), block 256 = 2 batches x 4 m-groups x 32 lanes.
// Each thread owns 4 h-cols (float4). cw computed for BOTH batches per Wrh read.
// ---------------------------------------------------------------------------
__global__ void k_phase2(const float* __restrict__ zx,
                         const float* __restrict__ zhp,
                         const float* __restrict__ Wrh,
                         const float* __restrict__ b_rp,
                         const float* __restrict__ b_wp,
                         const float* __restrict__ b_c,
                         const float* __restrict__ bh,
                         float* __restrict__ M2,
                         float* __restrict__ out,
                         int t, int tc, int CH, int T) {
  __shared__ float ar_s[2][M_BANK];
  __shared__ float aw_s[2][M_BANK];
  __shared__ float c_s[2][D_H];
  __shared__ float red[2][4][32][4];
  const int tid  = threadIdx.x;
  const int lane = tid & 31;
  const int grp  = tid >> 5;      // 0..7
  const int ba   = grp >> 2;      // batch-local 0..1
  const int mg   = grp & 3;       // m-group 0..3
  const int b0   = blockIdx.y * 2;
  const int b_g  = b0 + ba;
  const int s0   = blockIdx.x * 128 + lane * 4;
  const bool hz  = (t > 0);
  const size_t zxrow = (size_t)(b_g * CH + tc) * NPAD;

  // ---- softmaxes (each grp computes both for its batch; mg-redundant, identical)
  #pragma unroll
  for (int which = 0; which < 2; ++which) {
    float lv[4];
    float mx = -1e30f;
    #pragma unroll
    for (int i = 0; i < 4; ++i) {
      const int m = lane + i * 32;
      float l = -1e30f;
      if (m < M_BANK) {
        const int col = which * 100 + m;
        l = (which ? b_wp[m] : b_rp[m]) + zx[zxrow + col];
        if (hz) {
          #pragma unroll
          for (int p = 0; p < KSH; ++p)
            l += zhp[(size_t)(p * BATCH + b_g) * NPAD + col];
        }
      }
      lv[i] = l;
      mx = fmaxf(mx, l);
    }
    #pragma unroll
    for (int o = 16; o; o >>= 1) mx = fmaxf(mx, __shfl_xor(mx, o, 32));
    float sum = 0.f;
    #pragma unroll
    for (int i = 0; i < 4; ++i) {
      const float e = (lane + i * 32 < M_BANK) ? __expf(lv[i] - mx) : 0.f;
      lv[i] = e;
      sum += e;
    }
    #pragma unroll
    for (int o = 16; o; o >>= 1) sum += __shfl_xor(sum, o, 32);
    const float inv = 1.0f / sum;
    #pragma unroll
    for (int i = 0; i < 4; ++i) {
      const int m = lane + i * 32;
      if (m < M_BANK) {
        if (which) aw_s[ba][m] = lv[i] * inv;
        else       ar_s[ba][m] = lv[i] * inv;
      }
    }
  }
  // ---- stage c = relu(zc + b_c) for the block's 2 batches
  for (int idx = tid; idx < 2 * D_H; idx += 256) {
    const int bb = idx >> 9;
    const int k  = idx & 511;
    const int bg2 = b0 + bb;
    float v = b_c[k] + zx[(size_t)(bg2 * CH + tc) * NPAD + 200 + k];
    if (hz) {
      #pragma unroll
      for (int p = 0; p < KSH; ++p)
        v += zhp[(size_t)(p * BATCH + bg2) * NPAD + 200 + k];
    }
    c_s[bb][k] = fmaxf(v, 0.f);
  }
  __syncthreads();

  // ---- cw partials over this mg's k-quarter, both batches per Wrh read
  float cwa[4] = {};
  float cwb[4] = {};
  #pragma unroll 8
  for (int kk = 0; kk < 128; ++kk) {
    const int k = mg * 128 + kk;
    const float4 w = *reinterpret_cast<const float4*>(&Wrh[k * D_H + s0]);
    const float ca = c_s[0][k];
    const float cb = c_s[1][k];
    cwa[0] += ca * w.x; cwa[1] += ca * w.y; cwa[2] += ca * w.z; cwa[3] += ca * w.w;
    cwb[0] += cb * w.x; cwb[1] += cb * w.y; cwb[2] += cb * w.z; cwb[3] += cb * w.w;
  }
  #pragma unroll
  for (int j = 0; j < 4; ++j) {
    red[0][mg][lane][j] = cwa[j];
    red[1][mg][lane][j] = cwb[j];
  }
  __syncthreads();
  float cw[4];
  #pragma unroll
  for (int j = 0; j < 4; ++j)
    cw[j] = red[ba][0][lane][j] + red[ba][1][lane][j] +
            red[ba][2][lane][j] + red[ba][3][lane][j];
  __syncthreads();   // red re-used below

  // ---- M2 RMW (25 m-rows per thread) + racc partial
  float racc[4] = {};
  const int mbase = mg * 25;
  for (int mm = 0; mm < 25; ++mm) {
    const int m = mbase + mm;
    float* p = &M2[((size_t)b_g * M_BANK + m) * D_H + s0];
    const float4 v = *reinterpret_cast<const float4*>(p);
    const float a = ar_s[ba][m];
    const float w = aw_s[ba][m];
    racc[0] += a * v.x; racc[1] += a * v.y; racc[2] += a * v.z; racc[3] += a * v.w;
    float4 nv;
    nv.x = w * cw[0] + (1.f - w) * v.x;
    nv.y = w * cw[1] + (1.f - w) * v.y;
    nv.z = w * cw[2] + (1.f - w) * v.z;
    nv.w = w * cw[3] + (1.f - w) * v.w;
    *reinterpret_cast<float4*>(p) = nv;
  }
  #pragma unroll
  for (int j = 0; j < 4; ++j) red[ba][mg][lane][j] = racc[j];
  __syncthreads();

  if (mg == 0) {
    float ph[4];
    const float4 vb = *reinterpret_cast<const float4*>(&bh[s0]);
    const float4 px = *reinterpret_cast<const float4*>(&zx[zxrow + 712 + s0]);
    ph[0] = vb.x + px.x; ph[1] = vb.y + px.y;
    ph[2] = vb.z + px.z; ph[3] = vb.w + px.w;
    #pragma unroll
    for (int j = 0; j < 4; ++j)
      ph[j] += red[ba][0][lane][j] + red[ba][1][lane][j] +
               red[ba][2][lane][j] + red[ba][3][lane][j];
    if (hz) {
      #pragma unroll
      for (int p = 0; p < KSH; ++p) {
        const float4 pz = *reinterpret_cast<const float4*>(
            &zhp[(size_t)(p * BATCH + b_g) * NPAD + 712 + s0]);
        ph[0] += pz.x; ph[1] += pz.y; ph[2] += pz.z; ph[3] += pz.w;
      }
    }
    float4 h;
    h.x = fmaxf(ph[0], 0.f); h.y = fmaxf(ph[1], 0.f);
    h.z = fmaxf(ph[2], 0.f); h.w = fmaxf(ph[3], 0.f);
    *reinterpret_cast<float4*>(&out[((size_t)b_g * T + t) * D_H + s0]) = h;
  }
}

// ---------------------------------------------------------------------------
extern "C" void kernel_launch(void* const* d_in, const int* in_sizes, int n_in,
                              void* d_out, int out_size, void* d_ws, size_t ws_size,
                              hipStream_t stream) {
  const float* frames = (const float*)d_in[0];
  const float* W_c    = (const float*)d_in[1];
  const float* b_c    = (const float*)d_in[2];
  const float* W_rp   = (const float*)d_in[3];
  const float* b_rp   = (const float*)d_in[4];
  const float* W_wp   = (const float*)d_in[5];
  const float* b_wp   = (const float*)d_in[6];
  const float* Wxh    = (const float*)d_in[7];
  const float* Wrh    = (const float*)d_in[8];
  const float* Whh    = (const float*)d_in[9];
  const float* bh     = (const float*)d_in[10];
  float* out = (float*)d_out;

  const int TF = in_sizes[0] / (BATCH * D_IN);
  const int T  = out_size / (BATCH * D_H);

  const size_t M2_ELEMS  = (size_t)BATCH * M_BANK * D_H;      // 26.2 MB
  const size_t ZHP_ELEMS = (size_t)KSH * BATCH * NPAD;        // 2.6 MB
  float* M2  = (float*)d_ws;
  float* zhp = M2 + M2_ELEMS;
  float* zx  = zhp + ZHP_ELEMS;

  // pick largest chunk that fits ws and divides T
  int CH = 32, lgCH = 5;
  while (CH > 1 &&
         ((M2_ELEMS + ZHP_ELEMS + (size_t)BATCH * CH * NPAD) * sizeof(float) > ws_size ||
          (T % CH) != 0)) {
    CH >>= 1; --lgCH;
  }

  hipMemsetAsync(M2, 0, M2_ELEMS * sizeof(float), stream);

  for (int t0 = 0; t0 < T; t0 += CH) {
    k_zx<<<dim3(NPAD / 64, BATCH * CH / 64), 128, 0, stream>>>(
        frames, W_c, W_rp, W_wp, Wxh, Whh, zx, t0, CH, lgCH, TF);
    for (int t = t0; t < t0 + CH; ++t) {
      if (t > 0)
        k_zh<<<dim3(NPAD / 64, BATCH / 64, KSH), 128, 0, stream>>>(
            out, W_c, W_rp, W_wp, Wxh, Whh, zhp, t, T);
      k_phase2<<<dim3(D_H / 128, BATCH / 2), 256, 0, stream>>>(
          zx, zhp, Wrh, b_rp, b_wp, b_c, bh, M2, out, t, t - t0, CH, T);
    }
  }
}

// Round 4
// 7309.746 us; speedup vs baseline: 4.4961x; 1.6281x over previous
//
#include <hip/hip_runtime.h>

#define D_IN   1024
#define D_H    512
#define M_BANK 100
#define BATCH  128
#define NCOL   1224   // 100 rp | 100 wp | 512 c | 512 pre_h
#define NPAD   1280
#define KTOT   1536
#define KSH    2      // split-K partials for the per-step h-GEMM

typedef unsigned short u16;
typedef __attribute__((ext_vector_type(8))) short s16x8;
typedef __attribute__((ext_vector_type(4))) float f32x4;

__device__ __forceinline__ u16 f2bf(float f) {
  union { float f; unsigned int u; } v;
  v.f = f;
  unsigned int r = (v.u + 0x7FFFu + ((v.u >> 16) & 1u)) >> 16;
  return (u16)r;
}

// ---------------------------------------------------------------------------
// k_prep_w: W_bt[j][k] = bf16 of composite W[k][j], j in [0,1280), k in [0,1536)
//   cols [0,100)=W_rp [100,200)=W_wp [200,712)=W_c [712,1224)=Wxh/Whh else 0
// grid (1280, 6), block 256 (thread = one k)
// ---------------------------------------------------------------------------
__global__ void k_prep_w(const float* __restrict__ W_c,
                         const float* __restrict__ W_rp,
                         const float* __restrict__ W_wp,
                         const float* __restrict__ Wxh,
                         const float* __restrict__ Whh,
                         u16* __restrict__ W_bt) {
  const int j = blockIdx.x;
  const int k = blockIdx.y * 256 + threadIdx.x;
  float v = 0.f;
  if (j < 100)       v = W_rp[(size_t)k * M_BANK + j];
  else if (j < 200)  v = W_wp[(size_t)k * M_BANK + (j - 100)];
  else if (j < 712)  v = W_c[(size_t)k * D_H + (j - 200)];
  else if (j < NCOL) v = (k < D_IN) ? Wxh[(size_t)k * D_H + (j - 712)]
                                    : Whh[(size_t)(k - D_IN) * D_H + (j - 712)];
  W_bt[(size_t)j * KTOT + k] = f2bf(v);
}

// ---------------------------------------------------------------------------
// k_zx_mfma: hoisted x-GEMM, bf16 MFMA. zx[(b*CH+tc), j] = x @ W[0:1024, j]
// grid (NPAD/64, BATCH*CH/64), block 256 = 4 waves (2x2 of 32x32)
// ---------------------------------------------------------------------------
__global__ void k_zx_mfma(const float* __restrict__ frames,
                          const u16* __restrict__ W_bt,
                          float* __restrict__ zx,
                          int t0, int CH, int lgCH, int TF) {
  __shared__ u16 Asb[64][40];   // [row][k], pad to 40 (2-way conflicts only)
  __shared__ u16 Bsb[64][40];   // [col][k]
  const int tid  = threadIdx.x;
  const int lane = tid & 63;
  const int wid  = tid >> 6;
  const int wm   = wid >> 1, wn = wid & 1;
  const int j0 = blockIdx.x * 64;
  const int r0 = blockIdx.y * 64;
  const int srow = tid >> 2;          // 0..63
  const int skk  = (tid & 3) * 8;     // 0/8/16/24
  const int gr = r0 + srow;
  const int b  = gr >> lgCH;
  const int tc = gr & (CH - 1);
  const float* arow = &frames[((size_t)b * TF + t0 + tc) * D_IN];
  const u16*   brow = &W_bt[(size_t)(j0 + srow) * KTOT];

  f32x4 a00 = {0.f, 0.f, 0.f, 0.f}, a01 = {0.f, 0.f, 0.f, 0.f};
  f32x4 a10 = {0.f, 0.f, 0.f, 0.f}, a11 = {0.f, 0.f, 0.f, 0.f};

  for (int k0 = 0; k0 < D_IN; k0 += 32) {
    const float4 v0 = *reinterpret_cast<const float4*>(&arow[k0 + skk]);
    const float4 v1 = *reinterpret_cast<const float4*>(&arow[k0 + skk + 4]);
    s16x8 a8;
    a8[0] = (short)f2bf(v0.x); a8[1] = (short)f2bf(v0.y);
    a8[2] = (short)f2bf(v0.z); a8[3] = (short)f2bf(v0.w);
    a8[4] = (short)f2bf(v1.x); a8[5] = (short)f2bf(v1.y);
    a8[6] = (short)f2bf(v1.z); a8[7] = (short)f2bf(v1.w);
    *reinterpret_cast<s16x8*>(&Asb[srow][skk]) = a8;
    *reinterpret_cast<s16x8*>(&Bsb[srow][skk]) =
        *reinterpret_cast<const s16x8*>(&brow[k0 + skk]);
    __syncthreads();
    const int ka = (lane >> 4) * 8;
    const s16x8 af0 = *reinterpret_cast<s16x8*>(&Asb[wm * 32 + (lane & 15)][ka]);
    const s16x8 af1 = *reinterpret_cast<s16x8*>(&Asb[wm * 32 + 16 + (lane & 15)][ka]);
    const s16x8 bf0 = *reinterpret_cast<s16x8*>(&Bsb[wn * 32 + (lane & 15)][ka]);
    const s16x8 bf1 = *reinterpret_cast<s16x8*>(&Bsb[wn * 32 + 16 + (lane & 15)][ka]);
    a00 = __builtin_amdgcn_mfma_f32_16x16x32_bf16(af0, bf0, a00, 0, 0, 0);
    a01 = __builtin_amdgcn_mfma_f32_16x16x32_bf16(af0, bf1, a01, 0, 0, 0);
    a10 = __builtin_amdgcn_mfma_f32_16x16x32_bf16(af1, bf0, a10, 0, 0, 0);
    a11 = __builtin_amdgcn_mfma_f32_16x16x32_bf16(af1, bf1, a11, 0, 0, 0);
    __syncthreads();
  }
  const int rb = r0 + wm * 32 + (lane >> 4) * 4;
  const int cb = j0 + wn * 32 + (lane & 15);
#define STORE_ACC(A, MF, NF)                                             \
  {                                                                      \
    _Pragma("unroll")                                                    \
    for (int reg = 0; reg < 4; ++reg)                                    \
      zx[(size_t)(rb + MF * 16 + reg) * NPAD + cb + NF * 16] = A[reg];   \
  }
  STORE_ACC(a00, 0, 0) STORE_ACC(a01, 0, 1) STORE_ACC(a10, 1, 0) STORE_ACC(a11, 1, 1)
#undef STORE_ACC
}

// ---------------------------------------------------------------------------
// k_zh_mfma: per-step h-GEMM, bf16 MFMA, split-K=2.
//   zhp[kp][b, j] = h_bf[b, kslice] @ W[1024+kslice, j]
// grid (NPAD/64, BATCH/64, KSH), block 256
// ---------------------------------------------------------------------------
__global__ void k_zh_mfma(const u16* __restrict__ h_bf,
                          const u16* __restrict__ W_bt,
                          float* __restrict__ zhp) {
  __shared__ u16 Asb[64][40];
  __shared__ u16 Bsb[64][40];
  const int tid  = threadIdx.x;
  const int lane = tid & 63;
  const int wid  = tid >> 6;
  const int wm   = wid >> 1, wn = wid & 1;
  const int j0 = blockIdx.x * 64;
  const int r0 = blockIdx.y * 64;
  const int kp = blockIdx.z;
  const int srow = tid >> 2;
  const int skk  = (tid & 3) * 8;
  const u16* arow = &h_bf[(size_t)(r0 + srow) * D_H + kp * 256];
  const u16* brow = &W_bt[(size_t)(j0 + srow) * KTOT + D_IN + kp * 256];

  f32x4 a00 = {0.f, 0.f, 0.f, 0.f}, a01 = {0.f, 0.f, 0.f, 0.f};
  f32x4 a10 = {0.f, 0.f, 0.f, 0.f}, a11 = {0.f, 0.f, 0.f, 0.f};

  for (int kt = 0; kt < 256; kt += 32) {
    *reinterpret_cast<s16x8*>(&Asb[srow][skk]) =
        *reinterpret_cast<const s16x8*>(&arow[kt + skk]);
    *reinterpret_cast<s16x8*>(&Bsb[srow][skk]) =
        *reinterpret_cast<const s16x8*>(&brow[kt + skk]);
    __syncthreads();
    const int ka = (lane >> 4) * 8;
    const s16x8 af0 = *reinterpret_cast<s16x8*>(&Asb[wm * 32 + (lane & 15)][ka]);
    const s16x8 af1 = *reinterpret_cast<s16x8*>(&Asb[wm * 32 + 16 + (lane & 15)][ka]);
    const s16x8 bf0 = *reinterpret_cast<s16x8*>(&Bsb[wn * 32 + (lane & 15)][ka]);
    const s16x8 bf1 = *reinterpret_cast<s16x8*>(&Bsb[wn * 32 + 16 + (lane & 15)][ka]);
    a00 = __builtin_amdgcn_mfma_f32_16x16x32_bf16(af0, bf0, a00, 0, 0, 0);
    a01 = __builtin_amdgcn_mfma_f32_16x16x32_bf16(af0, bf1, a01, 0, 0, 0);
    a10 = __builtin_amdgcn_mfma_f32_16x16x32_bf16(af1, bf0, a10, 0, 0, 0);
    a11 = __builtin_amdgcn_mfma_f32_16x16x32_bf16(af1, bf1, a11, 0, 0, 0);
    __syncthreads();
  }
  const int rb = r0 + wm * 32 + (lane >> 4) * 4;
  const int cb = j0 + wn * 32 + (lane & 15);
  float* zp = &zhp[(size_t)kp * BATCH * NPAD];
#define STORE_ACC(A, MF, NF)                                             \
  {                                                                      \
    _Pragma("unroll")                                                    \
    for (int reg = 0; reg < 4; ++reg)                                    \
      zp[(size_t)(rb + MF * 16 + reg) * NPAD + cb + NF * 16] = A[reg];   \
  }
  STORE_ACC(a00, 0, 0) STORE_ACC(a01, 0, 1) STORE_ACC(a10, 1, 0) STORE_ACC(a11, 1, 1)
#undef STORE_ACC
}

// ---------------------------------------------------------------------------
// k_phase2: softmaxes, c, cw = c@Wrh, h' = relu(pre_h + ar@M2), M2 blend.
// grid (D_H/128, BATCH/2), block 256 = 2 batches x 4 m-groups x 32 lanes.
// ---------------------------------------------------------------------------
__global__ void k_phase2(const float* __restrict__ zx,
                         const float* __restrict__ zhp,
                         const float* __restrict__ Wrh,
                         const float* __restrict__ b_rp,
                         const float* __restrict__ b_wp,
                         const float* __restrict__ b_c,
                         const float* __restrict__ bh,
                         float* __restrict__ M2,
                         float* __restrict__ out,
                         u16* __restrict__ h_bf,
                         int t, int tc, int CH, int T) {
  __shared__ float ar_s[2][M_BANK];
  __shared__ float aw_s[2][M_BANK];
  __shared__ float c_s[2][D_H];
  __shared__ float red[2][4][32][4];
  const int tid  = threadIdx.x;
  const int lane = tid & 31;
  const int grp  = tid >> 5;
  const int ba   = grp >> 2;
  const int mg   = grp & 3;
  const int b0   = blockIdx.y * 2;
  const int b_g  = b0 + ba;
  const int s0   = blockIdx.x * 128 + lane * 4;
  const bool hz  = (t > 0);
  const size_t zxrow = (size_t)(b_g * CH + tc) * NPAD;

  #pragma unroll
  for (int which = 0; which < 2; ++which) {
    float lv[4];
    float mx = -1e30f;
    #pragma unroll
    for (int i = 0; i < 4; ++i) {
      const int m = lane + i * 32;
      float l = -1e30f;
      if (m < M_BANK) {
        const int col = which * 100 + m;
        l = (which ? b_wp[m] : b_rp[m]) + zx[zxrow + col];
        if (hz) {
          #pragma unroll
          for (int p = 0; p < KSH; ++p)
            l += zhp[(size_t)(p * BATCH + b_g) * NPAD + col];
        }
      }
      lv[i] = l;
      mx = fmaxf(mx, l);
    }
    #pragma unroll
    for (int o = 16; o; o >>= 1) mx = fmaxf(mx, __shfl_xor(mx, o, 32));
    float sum = 0.f;
    #pragma unroll
    for (int i = 0; i < 4; ++i) {
      const float e = (lane + i * 32 < M_BANK) ? __expf(lv[i] - mx) : 0.f;
      lv[i] = e;
      sum += e;
    }
    #pragma unroll
    for (int o = 16; o; o >>= 1) sum += __shfl_xor(sum, o, 32);
    const float inv = 1.0f / sum;
    #pragma unroll
    for (int i = 0; i < 4; ++i) {
      const int m = lane + i * 32;
      if (m < M_BANK) {
        if (which) aw_s[ba][m] = lv[i] * inv;
        else       ar_s[ba][m] = lv[i] * inv;
      }
    }
  }
  for (int idx = tid; idx < 2 * D_H; idx += 256) {
    const int bb = idx >> 9;
    const int k  = idx & 511;
    const int bg2 = b0 + bb;
    float v = b_c[k] + zx[(size_t)(bg2 * CH + tc) * NPAD + 200 + k];
    if (hz) {
      #pragma unroll
      for (int p = 0; p < KSH; ++p)
        v += zhp[(size_t)(p * BATCH + bg2) * NPAD + 200 + k];
    }
    c_s[bb][k] = fmaxf(v, 0.f);
  }
  __syncthreads();

  float cwa[4] = {};
  float cwb[4] = {};
  #pragma unroll 8
  for (int kk = 0; kk < 128; ++kk) {
    const int k = mg * 128 + kk;
    const float4 w = *reinterpret_cast<const float4*>(&Wrh[k * D_H + s0]);
    const float ca = c_s[0][k];
    const float cb = c_s[1][k];
    cwa[0] += ca * w.x; cwa[1] += ca * w.y; cwa[2] += ca * w.z; cwa[3] += ca * w.w;
    cwb[0] += cb * w.x; cwb[1] += cb * w.y; cwb[2] += cb * w.z; cwb[3] += cb * w.w;
  }
  #pragma unroll
  for (int j = 0; j < 4; ++j) {
    red[0][mg][lane][j] = cwa[j];
    red[1][mg][lane][j] = cwb[j];
  }
  __syncthreads();
  float cw[4];
  #pragma unroll
  for (int j = 0; j < 4; ++j)
    cw[j] = red[ba][0][lane][j] + red[ba][1][lane][j] +
            red[ba][2][lane][j] + red[ba][3][lane][j];
  __syncthreads();

  float racc[4] = {};
  const int mbase = mg * 25;
  for (int mm = 0; mm < 25; ++mm) {
    const int m = mbase + mm;
    float* p = &M2[((size_t)b_g * M_BANK + m) * D_H + s0];
    const float4 v = *reinterpret_cast<const float4*>(p);
    const float a = ar_s[ba][m];
    const float w = aw_s[ba][m];
    racc[0] += a * v.x; racc[1] += a * v.y; racc[2] += a * v.z; racc[3] += a * v.w;
    float4 nv;
    nv.x = w * cw[0] + (1.f - w) * v.x;
    nv.y = w * cw[1] + (1.f - w) * v.y;
    nv.z = w * cw[2] + (1.f - w) * v.z;
    nv.w = w * cw[3] + (1.f - w) * v.w;
    *reinterpret_cast<float4*>(p) = nv;
  }
  #pragma unroll
  for (int j = 0; j < 4; ++j) red[ba][mg][lane][j] = racc[j];
  __syncthreads();

  if (mg == 0) {
    float ph[4];
    const float4 vb = *reinterpret_cast<const float4*>(&bh[s0]);
    const float4 px = *reinterpret_cast<const float4*>(&zx[zxrow + 712 + s0]);
    ph[0] = vb.x + px.x; ph[1] = vb.y + px.y;
    ph[2] = vb.z + px.z; ph[3] = vb.w + px.w;
    #pragma unroll
    for (int j = 0; j < 4; ++j)
      ph[j] += red[ba][0][lane][j] + red[ba][1][lane][j] +
               red[ba][2][lane][j] + red[ba][3][lane][j];
    if (hz) {
      #pragma unroll
      for (int p = 0; p < KSH; ++p) {
        const float4 pz = *reinterpret_cast<const float4*>(
            &zhp[(size_t)(p * BATCH + b_g) * NPAD + 712 + s0]);
        ph[0] += pz.x; ph[1] += pz.y; ph[2] += pz.z; ph[3] += pz.w;
      }
    }
    float4 h;
    h.x = fmaxf(ph[0], 0.f); h.y = fmaxf(ph[1], 0.f);
    h.z = fmaxf(ph[2], 0.f); h.w = fmaxf(ph[3], 0.f);
    *reinterpret_cast<float4*>(&out[((size_t)b_g * T + t) * D_H + s0]) = h;
    ushort4 hb;
    hb.x = f2bf(h.x); hb.y = f2bf(h.y); hb.z = f2bf(h.z); hb.w = f2bf(h.w);
    *reinterpret_cast<ushort4*>(&h_bf[(size_t)b_g * D_H + s0]) = hb;
  }
}

// ---------------------------------------------------------------------------
extern "C" void kernel_launch(void* const* d_in, const int* in_sizes, int n_in,
                              void* d_out, int out_size, void* d_ws, size_t ws_size,
                              hipStream_t stream) {
  const float* frames = (const float*)d_in[0];
  const float* W_c    = (const float*)d_in[1];
  const float* b_c    = (const float*)d_in[2];
  const float* W_rp   = (const float*)d_in[3];
  const float* b_rp   = (const float*)d_in[4];
  const float* W_wp   = (const float*)d_in[5];
  const float* b_wp   = (const float*)d_in[6];
  const float* Wxh    = (const float*)d_in[7];
  const float* Wrh    = (const float*)d_in[8];
  const float* Whh    = (const float*)d_in[9];
  const float* bh     = (const float*)d_in[10];
  float* out = (float*)d_out;

  const int TF = in_sizes[0] / (BATCH * D_IN);
  const int T  = out_size / (BATCH * D_H);

  const size_t M2_ELEMS  = (size_t)BATCH * M_BANK * D_H;          // fl
  const size_t ZHP_ELEMS = (size_t)KSH * BATCH * NPAD;            // fl
  const size_t WBT_FL    = (size_t)NPAD * KTOT / 2;               // u16 as fl
  const size_t HBF_FL    = (size_t)BATCH * D_H / 2;               // u16 as fl

  float* M2  = (float*)d_ws;
  float* zhp = M2 + M2_ELEMS;
  float* zx  = zhp + ZHP_ELEMS;

  int CH = 32, lgCH = 5;
  while (CH > 1 &&
         ((M2_ELEMS + ZHP_ELEMS + WBT_FL + HBF_FL +
           (size_t)BATCH * CH * NPAD) * sizeof(float) > ws_size ||
          (T % CH) != 0)) {
    CH >>= 1; --lgCH;
  }

  u16* W_bt = (u16*)(zx + (size_t)BATCH * CH * NPAD);
  u16* h_bf = W_bt + (size_t)NPAD * KTOT;

  hipMemsetAsync(M2, 0, M2_ELEMS * sizeof(float), stream);
  k_prep_w<<<dim3(NPAD, KTOT / 256), 256, 0, stream>>>(W_c, W_rp, W_wp, Wxh, Whh, W_bt);

  for (int t0 = 0; t0 < T; t0 += CH) {
    k_zx_mfma<<<dim3(NPAD / 64, BATCH * CH / 64), 256, 0, stream>>>(
        frames, W_bt, zx, t0, CH, lgCH, TF);
    for (int t = t0; t < t0 + CH; ++t) {
      if (t > 0)
        k_zh_mfma<<<dim3(NPAD / 64, BATCH / 64, KSH), 256, 0, stream>>>(h_bf, W_bt, zhp);
      k_phase2<<<dim3(D_H / 128, BATCH / 2), 256, 0, stream>>>(
          zx, zhp, Wrh, b_rp, b_wp, b_c, bh, M2, out, h_bf, t, t - t0, CH, T);
    }
  }
}